// Round 10
// baseline (801.657 us; speedup 1.0000x reference)
//
#include <hip/hip_runtime.h>
#include <hip/hip_fp16.h>

#define NN 100000
#define NE 3200000
#define DF 128
#define HID 32
#define NBUK 391    // buckets of 256 nodes; bucket = dst >> 8
#define CAP 10240   // scr capacity per bucket (mean 8184, +22 sigma -> no overflow)
#define PEB 8192    // edges per k_part block (391 blocks)

// ws layout (4-byte words):
// [0, NN)            dis (float): rsqrt(deg+1)
// [NN, NN+400)       cursor (int): bucket write cursors; post-part = bucket ends
// [NN+400, 3NN+400)  h2 (float [NN,2], PRESCALED by dis)
// [3NN+400, 19NN+400)        h1 (fp16 [NN,32], PRESCALED by dis)
// [19NN+400, +NBUK*CAP)      scr: packed edges, bucket b at [b*CAP, cursor[b])
// total 19NN + 400 + 391*10240 = 5,904,240 words = 23.6 MB

__global__ void k_zc(int* __restrict__ cursor) {
    int i = threadIdx.x;
    if (i < NBUK) cursor[i] = i * CAP;
}

// partition edges into fixed-capacity bucket regions; packed = src | (dst&255)<<17
__global__ __launch_bounds__(512) void k_part(const int* __restrict__ eidx,
                                              int* __restrict__ cursor,
                                              unsigned* __restrict__ scr) {
    __shared__ unsigned h[NBUK];
    int tid = threadIdx.x;
    int base = blockIdx.x * PEB;
    for (int i = tid; i < NBUK; i += 512) h[i] = 0u;
    __syncthreads();
#pragma unroll
    for (int i = 0; i < PEB / 512; ++i) {
        int e = base + i * 512 + tid;
        if (e < NE) atomicAdd(&h[eidx[NE + e] >> 8], 1u);
    }
    __syncthreads();
    // one returning global atomic per (block,bucket)
    for (int i = tid; i < NBUK; i += 512) {
        unsigned c = h[i];
        h[i] = c ? (unsigned)atomicAdd(&cursor[i], (int)c) : 0u;
    }
    __syncthreads();
#pragma unroll
    for (int i = 0; i < PEB / 512; ++i) {
        int e = base + i * 512 + tid;
        if (e < NE) {
            int d = eidx[NE + e];
            unsigned pos = atomicAdd(&h[d >> 8], 1u);   // LDS returning atomic
            scr[pos] = (unsigned)eidx[e] | ((unsigned)(d & 255) << 17);
        }
    }
}

// per-node degree from own bucket segment -> dis
__global__ __launch_bounds__(256) void k_dis(const unsigned* __restrict__ scr,
                                             const int* __restrict__ cursor,
                                             float* __restrict__ dis) {
    int b = blockIdx.x;
    int cs = b * CAP, ce = cursor[b];
    __shared__ unsigned h[256];
    h[threadIdx.x] = 0u;
    __syncthreads();
    for (int j = cs + threadIdx.x; j < ce; j += 256)
        atomicAdd(&h[(scr[j] >> 17) & 255u], 1u);
    __syncthreads();
    int r = b * 256 + threadIdx.x;
    if (r < NN) dis[r] = rsqrtf((float)(h[threadIdx.x] + 1u));  // +1 = self-loop
}

// h1 = dis[r] * (x @ W1), fp16 [NN,32] (one 64B line per row)
__global__ __launch_bounds__(256) void k_gemm1(const float* __restrict__ x,
                                               const float* __restrict__ dis,
                                               const float* __restrict__ W1,
                                               __half* __restrict__ h1) {
    int r = blockIdx.x * blockDim.x + threadIdx.x;
    if (r >= NN) return;
    const float* xr = x + (size_t)r * DF;
    float acc[HID];
#pragma unroll
    for (int c = 0; c < HID; ++c) acc[c] = 0.f;
#pragma unroll
    for (int k = 0; k < DF; k += 4) {
        float4 xv = *reinterpret_cast<const float4*>(xr + k);
#pragma unroll
        for (int c = 0; c < HID; ++c) {
            acc[c] += xv.x * W1[(k + 0) * HID + c];
            acc[c] += xv.y * W1[(k + 1) * HID + c];
            acc[c] += xv.z * W1[(k + 2) * HID + c];
            acc[c] += xv.w * W1[(k + 3) * HID + c];
        }
    }
    float dr = dis[r];
    __half2 pack[HID / 2];
#pragma unroll
    for (int c = 0; c < HID; c += 2)
        pack[c / 2] = __floats2half2_rn(acc[c] * dr, acc[c + 1] * dr);
    float4* dstp = reinterpret_cast<float4*>(h1 + (size_t)r * HID);
    const float4* srcp = reinterpret_cast<const float4*>(pack);
#pragma unroll
    for (int i = 0; i < 4; ++i) dstp[i] = srcp[i];
}

// layer-1 aggregation: one block per bucket, LDS fp32 accumulators.
// per edge: 1 coalesced scr word + 1 random 64B h1 row + 2 ds_add_f32. No norm math.
// epilogue: val = sd[n]*(acc + own) + b1 -> relu -> @W2 -> h2 = sd[n]*out (prescaled).
__global__ __launch_bounds__(1024) void k_agg1(const unsigned* __restrict__ scr,
                                               const int* __restrict__ cursor,
                                               const float* __restrict__ dis,
                                               const __half* __restrict__ h1,
                                               const float* __restrict__ b1,
                                               const float* __restrict__ W2,
                                               float* __restrict__ h2) {
    int b = blockIdx.x;
    int cs = b * CAP, ce = cursor[b];
    __shared__ float acc[256 * HID];   // 32 KB
    __shared__ float sd[256];
    int tid = threadIdx.x;
    for (int i = tid; i < 256 * HID; i += 1024) acc[i] = 0.f;
    if (tid < 256) {
        int r = b * 256 + tid;
        sd[tid] = (r < NN) ? dis[r] : 0.f;
    }
    __syncthreads();
    int p = tid & 15, eg = tid >> 4;   // 64 edge-groups, 16 lanes (half2 each) per edge
    int j = cs + eg;
    for (; j + 64 < ce; j += 128) {    // 2-edge unroll per group
        unsigned wA = scr[j], wB = scr[j + 64];
        __half2 hA = *((const __half2*)(h1 + (size_t)(wA & 0x1FFFFu) * HID) + p);
        __half2 hB = *((const __half2*)(h1 + (size_t)(wB & 0x1FFFFu) * HID) + p);
        int dA = (int)((wA >> 17) & 255u), dB = (int)((wB >> 17) & 255u);
        float2 fA = __half22float2(hA), fB = __half22float2(hB);
        atomicAdd(&acc[dA * HID + 2 * p], fA.x);
        atomicAdd(&acc[dA * HID + 2 * p + 1], fA.y);
        atomicAdd(&acc[dB * HID + 2 * p], fB.x);
        atomicAdd(&acc[dB * HID + 2 * p + 1], fB.y);
    }
    if (j < ce) {
        unsigned wA = scr[j];
        __half2 hA = *((const __half2*)(h1 + (size_t)(wA & 0x1FFFFu) * HID) + p);
        int dA = (int)((wA >> 17) & 255u);
        float2 fA = __half22float2(hA);
        atomicAdd(&acc[dA * HID + 2 * p], fA.x);
        atomicAdd(&acc[dA * HID + 2 * p + 1], fA.y);
    }
    __syncthreads();
    if (tid < 256) {
        int r = b * 256 + tid;
        if (r < NN) {
            float s = sd[tid];
            const __half2* hr = (const __half2*)(h1 + (size_t)r * HID);
            float o0 = 0.f, o1 = 0.f;
#pragma unroll
            for (int c = 0; c < HID; c += 2) {
                float2 f = __half22float2(hr[c >> 1]);
                float v0 = fmaxf(s * (acc[tid * HID + c] + f.x) + b1[c], 0.f);
                float v1 = fmaxf(s * (acc[tid * HID + c + 1] + f.y) + b1[c + 1], 0.f);
                o0 += v0 * W2[c * 2 + 0] + v1 * W2[(c + 1) * 2 + 0];
                o1 += v0 * W2[c * 2 + 1] + v1 * W2[(c + 1) * 2 + 1];
            }
            h2[2 * (size_t)r + 0] = s * o0;   // prescale for layer 2
            h2[2 * (size_t)r + 1] = s * o1;
        }
    }
}

// layer-2 aggregation + log_softmax. h2 prescaled; acc split x/y to spread LDS banks.
__global__ __launch_bounds__(512) void k_agg2(const unsigned* __restrict__ scr,
                                              const int* __restrict__ cursor,
                                              const float* __restrict__ dis,
                                              const float* __restrict__ h2,
                                              const float* __restrict__ b2,
                                              float* __restrict__ out) {
    int b = blockIdx.x;
    int cs = b * CAP, ce = cursor[b];
    __shared__ float accx[256], accy[256], sd[256];
    int tid = threadIdx.x;
    if (tid < 256) {
        accx[tid] = 0.f;
        accy[tid] = 0.f;
        int r = b * 256 + tid;
        sd[tid] = (r < NN) ? dis[r] : 0.f;
    }
    __syncthreads();
    for (int j = cs + tid; j < ce; j += 512) {
        unsigned w = scr[j];
        float2 v = *(const float2*)(h2 + 2 * (size_t)(w & 0x1FFFFu));
        int dl = (int)((w >> 17) & 255u);
        atomicAdd(&accx[dl], v.x);
        atomicAdd(&accy[dl], v.y);
    }
    __syncthreads();
    if (tid < 256) {
        int r = b * 256 + tid;
        if (r < NN) {
            float s = sd[tid];
            float2 own = *(const float2*)(h2 + 2 * (size_t)r);
            float l0 = s * (accx[tid] + own.x) + b2[0];
            float l1 = s * (accy[tid] + own.y) + b2[1];
            float m = fmaxf(l0, l1);
            float lse = m + logf(expf(l0 - m) + expf(l1 - m));
            out[2 * (size_t)r + 0] = l0 - lse;
            out[2 * (size_t)r + 1] = l1 - lse;
        }
    }
}

extern "C" void kernel_launch(void* const* d_in, const int* in_sizes, int n_in,
                              void* d_out, int out_size, void* d_ws, size_t ws_size,
                              hipStream_t stream) {
    const float* x  = (const float*)d_in[0];
    const int* ei   = (const int*)d_in[1];   // [2, NE] int32
    const float* W1 = (const float*)d_in[2];
    const float* b1 = (const float*)d_in[3];
    const float* W2 = (const float*)d_in[4];
    const float* b2 = (const float*)d_in[5];
    float* out      = (float*)d_out;

    float* ws     = (float*)d_ws;
    float* dis    = ws;
    int* cursor   = (int*)(ws + (size_t)NN);
    float* h2     = ws + (size_t)NN + 400;
    __half* h1    = (__half*)(ws + (size_t)3 * NN + 400);
    unsigned* scr = (unsigned*)(ws + (size_t)19 * NN + 400);

    k_zc<<<1, 512, 0, stream>>>(cursor);
    k_part<<<(NE + PEB - 1) / PEB, 512, 0, stream>>>(ei, cursor, scr);
    k_dis<<<NBUK, 256, 0, stream>>>(scr, cursor, dis);
    k_gemm1<<<(NN + 255) / 256, 256, 0, stream>>>(x, dis, W1, h1);
    k_agg1<<<NBUK, 1024, 0, stream>>>(scr, cursor, dis, h1, b1, W2, h2);
    k_agg2<<<NBUK, 512, 0, stream>>>(scr, cursor, dis, h2, b2, out);
}

// Round 11
// 163.220 us; speedup vs baseline: 4.9115x; 4.9115x over previous
//
#include <hip/hip_runtime.h>
#include <hip/hip_fp16.h>

#define NN 100000
#define NE 3200000
#define DF 128
#define HID 32
#define NC 2
#define NBUK 391    // buckets of 256 nodes; bucket = dst >> 8
#define CAP 10240   // scr capacity per bucket (mean 8184, +22 sigma -> no overflow)
#define PEB 8192    // edges per k_part block (391 blocks)

// ws layout (4-byte words):
// [0, NN)              dis (float): rsqrt(deg+1)
// [NN, 2NN)            rofs (int): per-node edge-list start (CAP-strided space)
// [2NN, 3NN)           rend (int): per-node edge-list end
// [3NN, 3NN+400)       cursor (int): bucket cursors; post-part = bucket ends
// [3NN+400, 5NN+400)   h2 (float [NN,2], PRESCALED by dis)
// [5NN+400, 21NN+400)  h1 (fp16 [NN,32], PRESCALED by dis)
// [21NN+400, +NBUK*CAP) scr: packed edges -> (in-place, after k_build) csr
// total 21NN + 400 + 391*10240 = 6,104,240 words = 24.4 MB

__global__ void k_zc(int* __restrict__ cursor) {
    int i = threadIdx.x;
    if (i < NBUK) cursor[i] = i * CAP;
}

// partition edges into fixed-capacity bucket regions; packed = src | (dst&255)<<17
__global__ __launch_bounds__(512) void k_part(const int* __restrict__ eidx,
                                              int* __restrict__ cursor,
                                              unsigned* __restrict__ scr) {
    __shared__ unsigned h[NBUK];
    int tid = threadIdx.x;
    int base = blockIdx.x * PEB;
    for (int i = tid; i < NBUK; i += 512) h[i] = 0u;
    __syncthreads();
#pragma unroll
    for (int i = 0; i < PEB / 512; ++i) {
        int e = base + i * 512 + tid;
        if (e < NE) atomicAdd(&h[eidx[NE + e] >> 8], 1u);
    }
    __syncthreads();
    // one returning global atomic per (block,bucket)
    for (int i = tid; i < NBUK; i += 512) {
        unsigned c = h[i];
        h[i] = c ? (unsigned)atomicAdd(&cursor[i], (int)c) : 0u;
    }
    __syncthreads();
#pragma unroll
    for (int i = 0; i < PEB / 512; ++i) {
        int e = base + i * 512 + tid;
        if (e < NE) {
            int d = eidx[NE + e];
            unsigned pos = atomicAdd(&h[d >> 8], 1u);   // LDS int atomic (native)
            scr[pos] = (unsigned)eidx[e] | ((unsigned)(d & 255) << 17);
        }
    }
}

// one block per bucket: stage segment in LDS, 256-bin hist -> rofs/rend/dis,
// ranked scatter back IN PLACE (csr overwrites scr; all reads staged first).
__global__ __launch_bounds__(256) void k_build(unsigned* __restrict__ scr,
                                               const int* __restrict__ cursor,
                                               int* __restrict__ rofs, int* __restrict__ rend,
                                               float* __restrict__ dis) {
    int b = blockIdx.x;
    int cs = b * CAP, ce = cursor[b];
    int n = ce - cs;
    __shared__ unsigned stage[CAP];    // 40 KB
    __shared__ unsigned h[256];
    __shared__ int sm[256];
    int tid = threadIdx.x;
    h[tid] = 0u;
    __syncthreads();
    for (int j = tid; j < n; j += 256) {
        unsigned w = scr[cs + j];
        stage[j] = w;
        atomicAdd(&h[(w >> 17) & 255u], 1u);
    }
    __syncthreads();
    int v = (int)h[tid];
    sm[tid] = v;
    __syncthreads();
    for (int off = 1; off < 256; off <<= 1) {
        int t = (tid >= off) ? sm[tid - off] : 0;
        __syncthreads();
        sm[tid] += t;
        __syncthreads();
    }
    int excl = sm[tid] - v;
    int node = b * 256 + tid;
    if (node < NN) {
        rofs[node] = cs + excl;
        rend[node] = cs + excl + v;
        dis[node] = rsqrtf((float)(v + 1));   // +1 = self-loop
    }
    __syncthreads();
    h[tid] = (unsigned)(cs + excl);   // reuse as per-node cursor
    __syncthreads();
    for (int j = tid; j < n; j += 256) {
        unsigned w = stage[j];
        unsigned pos = atomicAdd(&h[(w >> 17) & 255u], 1u);
        scr[pos] = w & 0x1FFFFu;      // csr: src index, node-grouped
    }
}

// h1 = dis[r] * (x @ W1), fp16 [NN,32] (one 64B line per row, prescaled)
__global__ __launch_bounds__(256) void k_gemm1(const float* __restrict__ x,
                                               const float* __restrict__ dis,
                                               const float* __restrict__ W1,
                                               __half* __restrict__ h1) {
    int r = blockIdx.x * blockDim.x + threadIdx.x;
    if (r >= NN) return;
    const float* xr = x + (size_t)r * DF;
    float acc[HID];
#pragma unroll
    for (int c = 0; c < HID; ++c) acc[c] = 0.f;
#pragma unroll
    for (int k = 0; k < DF; k += 4) {
        float4 xv = *reinterpret_cast<const float4*>(xr + k);
#pragma unroll
        for (int c = 0; c < HID; ++c) {
            acc[c] += xv.x * W1[(k + 0) * HID + c];
            acc[c] += xv.y * W1[(k + 1) * HID + c];
            acc[c] += xv.z * W1[(k + 2) * HID + c];
            acc[c] += xv.w * W1[(k + 3) * HID + c];
        }
    }
    float dr = dis[r];
    __half2 pack[HID / 2];
#pragma unroll
    for (int c = 0; c < HID; c += 2)
        pack[c / 2] = __floats2half2_rn(acc[c] * dr, acc[c + 1] * dr);
    float4* dstp = reinterpret_cast<float4*>(h1 + (size_t)r * HID);
    const float4* srcp = reinterpret_cast<const float4*>(pack);
#pragma unroll
    for (int i = 0; i < 4; ++i) dstp[i] = srcp[i];
}

// gather-aggregate layer 1: 4 lanes/edge x float4 (64B fp16 row), 8-edge unroll.
// h1 prescaled -> per edge: csr word + ONE random 64B row, no dis load, no mult.
__global__ void k_gather1(const int* __restrict__ rofs, const int* __restrict__ rend,
                          const int* __restrict__ csr, const float* __restrict__ dis,
                          const __half* __restrict__ h1, const float* __restrict__ b1,
                          const float* __restrict__ W2, float* __restrict__ h2) {
    int t = blockIdx.x * blockDim.x + threadIdx.x;
    int r = t >> 2;
    if (r >= NN) return;
    int p = t & 3;
    const float4* hv = reinterpret_cast<const float4*>(h1);
    int start = rofs[r];
    int end = rend[r];
    float a[8];
#pragma unroll
    for (int k = 0; k < 8; ++k) a[k] = 0.f;

#define ACC4(q)                                                           \
    {                                                                     \
        const __half2* hp = reinterpret_cast<const __half2*>(&(q));       \
        _Pragma("unroll") for (int k = 0; k < 4; ++k) {                   \
            float2 f = __half22float2(hp[k]);                             \
            a[2 * k] += f.x;                                              \
            a[2 * k + 1] += f.y;                                          \
        }                                                                 \
    }

    int j = start;
    for (; j + 7 < end; j += 8) {
        int s0 = csr[j], s1 = csr[j + 1], s2 = csr[j + 2], s3 = csr[j + 3];
        int s4 = csr[j + 4], s5 = csr[j + 5], s6 = csr[j + 6], s7 = csr[j + 7];
        float4 q0 = hv[(size_t)s0 * 4 + p];
        float4 q1 = hv[(size_t)s1 * 4 + p];
        float4 q2 = hv[(size_t)s2 * 4 + p];
        float4 q3 = hv[(size_t)s3 * 4 + p];
        float4 q4 = hv[(size_t)s4 * 4 + p];
        float4 q5 = hv[(size_t)s5 * 4 + p];
        float4 q6 = hv[(size_t)s6 * 4 + p];
        float4 q7 = hv[(size_t)s7 * 4 + p];
        ACC4(q0) ACC4(q1) ACC4(q2) ACC4(q3)
        ACC4(q4) ACC4(q5) ACC4(q6) ACC4(q7)
    }
    for (; j < end; ++j) {
        int s0 = csr[j];
        float4 q0 = hv[(size_t)s0 * 4 + p];
        ACC4(q0)
    }
    float4 qs = hv[(size_t)r * 4 + p];   // self term (h1p[r])
    ACC4(qs)
#undef ACC4

    float dr = dis[r];
    int c = p * 8;
    float4 bl = *reinterpret_cast<const float4*>(b1 + c);
    float4 bh = *reinterpret_cast<const float4*>(b1 + c + 4);
    float vv[8];
    vv[0] = fmaxf(dr * a[0] + bl.x, 0.f); vv[1] = fmaxf(dr * a[1] + bl.y, 0.f);
    vv[2] = fmaxf(dr * a[2] + bl.z, 0.f); vv[3] = fmaxf(dr * a[3] + bl.w, 0.f);
    vv[4] = fmaxf(dr * a[4] + bh.x, 0.f); vv[5] = fmaxf(dr * a[5] + bh.y, 0.f);
    vv[6] = fmaxf(dr * a[6] + bh.z, 0.f); vv[7] = fmaxf(dr * a[7] + bh.w, 0.f);
    float o0 = 0.f, o1 = 0.f;
#pragma unroll
    for (int k = 0; k < 8; ++k) {
        o0 += vv[k] * W2[(c + k) * NC + 0];
        o1 += vv[k] * W2[(c + k) * NC + 1];
    }
    o0 += __shfl_xor(o0, 1); o1 += __shfl_xor(o1, 1);
    o0 += __shfl_xor(o0, 2); o1 += __shfl_xor(o1, 2);
    if (p == 0) {
        h2[2 * (size_t)r + 0] = dr * o0;   // prescale for layer 2
        h2[2 * (size_t)r + 1] = dr * o1;
    }
}

// gather-aggregate layer 2 (h2 prescaled) + log_softmax -> out
__global__ void k_gather2(const int* __restrict__ rofs, const int* __restrict__ rend,
                          const int* __restrict__ csr, const float* __restrict__ dis,
                          const float* __restrict__ h2, const float* __restrict__ b2,
                          float* __restrict__ out) {
    int r = blockIdx.x * blockDim.x + threadIdx.x;
    if (r >= NN) return;
    int start = rofs[r], end = rend[r];
    float a0 = 0.f, a1 = 0.f;
    int j = start;
    for (; j + 3 < end; j += 4) {
        int s0 = csr[j], s1 = csr[j + 1], s2 = csr[j + 2], s3 = csr[j + 3];
        float2 v0 = *(const float2*)(h2 + 2 * (size_t)s0);
        float2 v1 = *(const float2*)(h2 + 2 * (size_t)s1);
        float2 v2 = *(const float2*)(h2 + 2 * (size_t)s2);
        float2 v3 = *(const float2*)(h2 + 2 * (size_t)s3);
        a0 += v0.x + v1.x + v2.x + v3.x;
        a1 += v0.y + v1.y + v2.y + v3.y;
    }
    for (; j < end; ++j) {
        float2 v = *(const float2*)(h2 + 2 * (size_t)csr[j]);
        a0 += v.x;
        a1 += v.y;
    }
    float dr = dis[r];
    float2 own = *(const float2*)(h2 + 2 * (size_t)r);
    float l0 = dr * (a0 + own.x) + b2[0];
    float l1 = dr * (a1 + own.y) + b2[1];
    float m = fmaxf(l0, l1);
    float lse = m + logf(expf(l0 - m) + expf(l1 - m));
    out[2 * (size_t)r + 0] = l0 - lse;
    out[2 * (size_t)r + 1] = l1 - lse;
}

extern "C" void kernel_launch(void* const* d_in, const int* in_sizes, int n_in,
                              void* d_out, int out_size, void* d_ws, size_t ws_size,
                              hipStream_t stream) {
    const float* x  = (const float*)d_in[0];
    const int* ei   = (const int*)d_in[1];   // [2, NE] int32
    const float* W1 = (const float*)d_in[2];
    const float* b1 = (const float*)d_in[3];
    const float* W2 = (const float*)d_in[4];
    const float* b2 = (const float*)d_in[5];
    float* out      = (float*)d_out;

    float* ws     = (float*)d_ws;
    float* dis    = ws;
    int* rofs     = (int*)(ws + (size_t)NN);
    int* rend     = (int*)(ws + (size_t)2 * NN);
    int* cursor   = (int*)(ws + (size_t)3 * NN);
    float* h2     = ws + (size_t)3 * NN + 400;
    __half* h1    = (__half*)(ws + (size_t)5 * NN + 400);
    unsigned* scr = (unsigned*)(ws + (size_t)21 * NN + 400);  // -> csr in place

    k_zc<<<1, 512, 0, stream>>>(cursor);
    k_part<<<(NE + PEB - 1) / PEB, 512, 0, stream>>>(ei, cursor, scr);
    k_build<<<NBUK, 256, 0, stream>>>(scr, cursor, rofs, rend, dis);
    k_gemm1<<<(NN + 255) / 256, 256, 0, stream>>>(x, dis, W1, h1);
    k_gather1<<<(NN * 4 + 255) / 256, 256, 0, stream>>>(rofs, rend, (const int*)scr, dis, h1, b1, W2, h2);
    k_gather2<<<(NN + 255) / 256, 256, 0, stream>>>(rofs, rend, (const int*)scr, dis, h2, b2, out);
}

// Round 12
// 155.456 us; speedup vs baseline: 5.1568x; 1.0499x over previous
//
#include <hip/hip_runtime.h>
#include <hip/hip_fp16.h>

#define NN 100000
#define NE 3200000
#define DF 128
#define HID 32
#define NC 2
#define NBUK 391    // buckets of 256 nodes; bucket = dst >> 8
#define CAP 10240   // scr capacity per bucket (mean 8184, +22 sigma -> no overflow)
#define PEB 8192    // edges per k_part block (391 blocks)

// ws layout (4-byte words):
// [0, NN)              dis (float): rsqrt(deg+1)
// [NN, 2NN)            rofs (int): per-node edge-list start (CAP-strided space)
// [2NN, 3NN)           rend (int): per-node edge-list end
// [3NN, 3NN+400)       cursor (int): bucket cursors; post-part = bucket ends
// [3NN+400, 5NN+400)   h2 (float [NN,2], PRESCALED by dis)
// [5NN+400, 21NN+400)  h1 (fp16 [NN,32], PRESCALED by dis)
// [21NN+400, +NBUK*CAP) scr: packed edges -> (in-place, after k_build) csr
// total 21NN + 400 + 391*10240 = 6,104,240 words = 24.4 MB

__global__ void k_zc(int* __restrict__ cursor) {
    int i = threadIdx.x;
    if (i < NBUK) cursor[i] = i * CAP;
}

// partition edges into fixed-capacity bucket regions.
// LDS-sort by bucket, then per-warp COALESCED run emission (runs ~21 words).
// packed word = src | (dst&255)<<17
__global__ __launch_bounds__(512) void k_part(const int* __restrict__ eidx,
                                              int* __restrict__ cursor,
                                              unsigned* __restrict__ scr) {
    __shared__ unsigned hist[NBUK];      // counts -> global bases
    __shared__ unsigned lofs[NBUK + 1];  // local exclusive offsets (+ total sentinel)
    __shared__ unsigned aux[NBUK];       // local scatter cursor
    __shared__ unsigned stage[PEB];      // 32 KB bucket-sorted stage
    __shared__ int sm[512];
    int tid = threadIdx.x;
    int base = blockIdx.x * PEB;

    for (int i = tid; i < NBUK; i += 512) hist[i] = 0u;
    __syncthreads();

    int s[PEB / 512], d[PEB / 512];
#pragma unroll
    for (int i = 0; i < PEB / 512; ++i) {
        int e = base + i * 512 + tid;
        if (e < NE) {
            s[i] = eidx[e];
            d[i] = eidx[NE + e];
            atomicAdd(&hist[d[i] >> 8], 1u);
        } else d[i] = -1;
    }
    __syncthreads();

    // exclusive scan of the 391 counts (512-wide Hillis-Steele)
    int v = (tid < NBUK) ? (int)hist[tid] : 0;
    sm[tid] = v;
    __syncthreads();
    for (int off = 1; off < 512; off <<= 1) {
        int t = (tid >= off) ? sm[tid - off] : 0;
        __syncthreads();
        sm[tid] += t;
        __syncthreads();
    }
    if (tid < NBUK) {
        unsigned excl = (unsigned)(sm[tid] - v);
        lofs[tid] = excl;
        aux[tid] = excl;
    }
    if (tid == 511) lofs[NBUK] = (unsigned)sm[511];  // total valid edges
    __syncthreads();

    // LDS scatter -> bucket-sorted stage
#pragma unroll
    for (int i = 0; i < PEB / 512; ++i) {
        if (d[i] >= 0) {
            unsigned lpos = atomicAdd(&aux[d[i] >> 8], 1u);
            stage[lpos] = (unsigned)s[i] | ((unsigned)(d[i] & 255) << 17);
        }
    }
    __syncthreads();

    // reserve global space: one returning atomic per nonzero bucket
    for (int i = tid; i < NBUK; i += 512) {
        unsigned c = hist[i];
        hist[i] = c ? (unsigned)atomicAdd(&cursor[i], (int)c) : 0u;
    }
    __syncthreads();

    // per-warp run emission: consecutive lanes -> consecutive addresses
    int warp = tid >> 6, lane = tid & 63;
    for (int i = warp; i < NBUK; i += 8) {
        unsigned lo = lofs[i];
        unsigned n = lofs[i + 1] - lo;
        unsigned gbase = hist[i];
        for (unsigned k = lane; k < n; k += 64)
            scr[gbase + k] = stage[lo + k];
    }
}

// one block per bucket: stage segment in LDS, 256-bin hist -> rofs/rend/dis,
// ranked scatter back IN PLACE (csr overwrites scr; all reads staged first).
__global__ __launch_bounds__(256) void k_build(unsigned* __restrict__ scr,
                                               const int* __restrict__ cursor,
                                               int* __restrict__ rofs, int* __restrict__ rend,
                                               float* __restrict__ dis) {
    int b = blockIdx.x;
    int cs = b * CAP, ce = cursor[b];
    int n = ce - cs;
    __shared__ unsigned stage[CAP];    // 40 KB
    __shared__ unsigned h[256];
    __shared__ int sm[256];
    int tid = threadIdx.x;
    h[tid] = 0u;
    __syncthreads();
    for (int j = tid; j < n; j += 256) {
        unsigned w = scr[cs + j];
        stage[j] = w;
        atomicAdd(&h[(w >> 17) & 255u], 1u);
    }
    __syncthreads();
    int v = (int)h[tid];
    sm[tid] = v;
    __syncthreads();
    for (int off = 1; off < 256; off <<= 1) {
        int t = (tid >= off) ? sm[tid - off] : 0;
        __syncthreads();
        sm[tid] += t;
        __syncthreads();
    }
    int excl = sm[tid] - v;
    int node = b * 256 + tid;
    if (node < NN) {
        rofs[node] = cs + excl;
        rend[node] = cs + excl + v;
        dis[node] = rsqrtf((float)(v + 1));   // +1 = self-loop
    }
    __syncthreads();
    h[tid] = (unsigned)(cs + excl);   // reuse as per-node cursor
    __syncthreads();
    for (int j = tid; j < n; j += 256) {
        unsigned w = stage[j];
        unsigned pos = atomicAdd(&h[(w >> 17) & 255u], 1u);
        scr[pos] = w & 0x1FFFFu;      // csr: src index, node-grouped
    }
}

// h1 = dis[r] * (x @ W1), fp16 [NN,32] (one 64B line per row, prescaled)
__global__ __launch_bounds__(256) void k_gemm1(const float* __restrict__ x,
                                               const float* __restrict__ dis,
                                               const float* __restrict__ W1,
                                               __half* __restrict__ h1) {
    int r = blockIdx.x * blockDim.x + threadIdx.x;
    if (r >= NN) return;
    const float* xr = x + (size_t)r * DF;
    float acc[HID];
#pragma unroll
    for (int c = 0; c < HID; ++c) acc[c] = 0.f;
#pragma unroll
    for (int k = 0; k < DF; k += 4) {
        float4 xv = *reinterpret_cast<const float4*>(xr + k);
#pragma unroll
        for (int c = 0; c < HID; ++c) {
            acc[c] += xv.x * W1[(k + 0) * HID + c];
            acc[c] += xv.y * W1[(k + 1) * HID + c];
            acc[c] += xv.z * W1[(k + 2) * HID + c];
            acc[c] += xv.w * W1[(k + 3) * HID + c];
        }
    }
    float dr = dis[r];
    __half2 pack[HID / 2];
#pragma unroll
    for (int c = 0; c < HID; c += 2)
        pack[c / 2] = __floats2half2_rn(acc[c] * dr, acc[c + 1] * dr);
    float4* dstp = reinterpret_cast<float4*>(h1 + (size_t)r * HID);
    const float4* srcp = reinterpret_cast<const float4*>(pack);
#pragma unroll
    for (int i = 0; i < 4; ++i) dstp[i] = srcp[i];
}

// gather-aggregate layer 1: 4 lanes/edge x float4 (64B fp16 row), 8-edge unroll.
// h1 prescaled -> per edge: csr word + ONE random 64B row, no dis load, no mult.
__global__ void k_gather1(const int* __restrict__ rofs, const int* __restrict__ rend,
                          const int* __restrict__ csr, const float* __restrict__ dis,
                          const __half* __restrict__ h1, const float* __restrict__ b1,
                          const float* __restrict__ W2, float* __restrict__ h2) {
    int t = blockIdx.x * blockDim.x + threadIdx.x;
    int r = t >> 2;
    if (r >= NN) return;
    int p = t & 3;
    const float4* hv = reinterpret_cast<const float4*>(h1);
    int start = rofs[r];
    int end = rend[r];
    float a[8];
#pragma unroll
    for (int k = 0; k < 8; ++k) a[k] = 0.f;

#define ACC4(q)                                                           \
    {                                                                     \
        const __half2* hp = reinterpret_cast<const __half2*>(&(q));       \
        _Pragma("unroll") for (int k = 0; k < 4; ++k) {                   \
            float2 f = __half22float2(hp[k]);                             \
            a[2 * k] += f.x;                                              \
            a[2 * k + 1] += f.y;                                          \
        }                                                                 \
    }

    int j = start;
    for (; j + 7 < end; j += 8) {
        int s0 = csr[j], s1 = csr[j + 1], s2 = csr[j + 2], s3 = csr[j + 3];
        int s4 = csr[j + 4], s5 = csr[j + 5], s6 = csr[j + 6], s7 = csr[j + 7];
        float4 q0 = hv[(size_t)s0 * 4 + p];
        float4 q1 = hv[(size_t)s1 * 4 + p];
        float4 q2 = hv[(size_t)s2 * 4 + p];
        float4 q3 = hv[(size_t)s3 * 4 + p];
        float4 q4 = hv[(size_t)s4 * 4 + p];
        float4 q5 = hv[(size_t)s5 * 4 + p];
        float4 q6 = hv[(size_t)s6 * 4 + p];
        float4 q7 = hv[(size_t)s7 * 4 + p];
        ACC4(q0) ACC4(q1) ACC4(q2) ACC4(q3)
        ACC4(q4) ACC4(q5) ACC4(q6) ACC4(q7)
    }
    for (; j < end; ++j) {
        int s0 = csr[j];
        float4 q0 = hv[(size_t)s0 * 4 + p];
        ACC4(q0)
    }
    float4 qs = hv[(size_t)r * 4 + p];   // self term (h1p[r])
    ACC4(qs)
#undef ACC4

    float dr = dis[r];
    int c = p * 8;
    float4 bl = *reinterpret_cast<const float4*>(b1 + c);
    float4 bh = *reinterpret_cast<const float4*>(b1 + c + 4);
    float vv[8];
    vv[0] = fmaxf(dr * a[0] + bl.x, 0.f); vv[1] = fmaxf(dr * a[1] + bl.y, 0.f);
    vv[2] = fmaxf(dr * a[2] + bl.z, 0.f); vv[3] = fmaxf(dr * a[3] + bl.w, 0.f);
    vv[4] = fmaxf(dr * a[4] + bh.x, 0.f); vv[5] = fmaxf(dr * a[5] + bh.y, 0.f);
    vv[6] = fmaxf(dr * a[6] + bh.z, 0.f); vv[7] = fmaxf(dr * a[7] + bh.w, 0.f);
    float o0 = 0.f, o1 = 0.f;
#pragma unroll
    for (int k = 0; k < 8; ++k) {
        o0 += vv[k] * W2[(c + k) * NC + 0];
        o1 += vv[k] * W2[(c + k) * NC + 1];
    }
    o0 += __shfl_xor(o0, 1); o1 += __shfl_xor(o1, 1);
    o0 += __shfl_xor(o0, 2); o1 += __shfl_xor(o1, 2);
    if (p == 0) {
        h2[2 * (size_t)r + 0] = dr * o0;   // prescale for layer 2
        h2[2 * (size_t)r + 1] = dr * o1;
    }
}

// gather-aggregate layer 2 (h2 prescaled) + log_softmax -> out
__global__ void k_gather2(const int* __restrict__ rofs, const int* __restrict__ rend,
                          const int* __restrict__ csr, const float* __restrict__ dis,
                          const float* __restrict__ h2, const float* __restrict__ b2,
                          float* __restrict__ out) {
    int r = blockIdx.x * blockDim.x + threadIdx.x;
    if (r >= NN) return;
    int start = rofs[r], end = rend[r];
    float a0 = 0.f, a1 = 0.f;
    int j = start;
    for (; j + 3 < end; j += 4) {
        int s0 = csr[j], s1 = csr[j + 1], s2 = csr[j + 2], s3 = csr[j + 3];
        float2 v0 = *(const float2*)(h2 + 2 * (size_t)s0);
        float2 v1 = *(const float2*)(h2 + 2 * (size_t)s1);
        float2 v2 = *(const float2*)(h2 + 2 * (size_t)s2);
        float2 v3 = *(const float2*)(h2 + 2 * (size_t)s3);
        a0 += v0.x + v1.x + v2.x + v3.x;
        a1 += v0.y + v1.y + v2.y + v3.y;
    }
    for (; j < end; ++j) {
        float2 v = *(const float2*)(h2 + 2 * (size_t)csr[j]);
        a0 += v.x;
        a1 += v.y;
    }
    float dr = dis[r];
    float2 own = *(const float2*)(h2 + 2 * (size_t)r);
    float l0 = dr * (a0 + own.x) + b2[0];
    float l1 = dr * (a1 + own.y) + b2[1];
    float m = fmaxf(l0, l1);
    float lse = m + logf(expf(l0 - m) + expf(l1 - m));
    out[2 * (size_t)r + 0] = l0 - lse;
    out[2 * (size_t)r + 1] = l1 - lse;
}

extern "C" void kernel_launch(void* const* d_in, const int* in_sizes, int n_in,
                              void* d_out, int out_size, void* d_ws, size_t ws_size,
                              hipStream_t stream) {
    const float* x  = (const float*)d_in[0];
    const int* ei   = (const int*)d_in[1];   // [2, NE] int32
    const float* W1 = (const float*)d_in[2];
    const float* b1 = (const float*)d_in[3];
    const float* W2 = (const float*)d_in[4];
    const float* b2 = (const float*)d_in[5];
    float* out      = (float*)d_out;

    float* ws     = (float*)d_ws;
    float* dis    = ws;
    int* rofs     = (int*)(ws + (size_t)NN);
    int* rend     = (int*)(ws + (size_t)2 * NN);
    int* cursor   = (int*)(ws + (size_t)3 * NN);
    float* h2     = ws + (size_t)3 * NN + 400;
    __half* h1    = (__half*)(ws + (size_t)5 * NN + 400);
    unsigned* scr = (unsigned*)(ws + (size_t)21 * NN + 400);  // -> csr in place

    k_zc<<<1, 512, 0, stream>>>(cursor);
    k_part<<<(NE + PEB - 1) / PEB, 512, 0, stream>>>(ei, cursor, scr);
    k_build<<<NBUK, 256, 0, stream>>>(scr, cursor, rofs, rend, dis);
    k_gemm1<<<(NN + 255) / 256, 256, 0, stream>>>(x, dis, W1, h1);
    k_gather1<<<(NN * 4 + 255) / 256, 256, 0, stream>>>(rofs, rend, (const int*)scr, dis, h1, b1, W2, h2);
    k_gather2<<<(NN + 255) / 256, 256, 0, stream>>>(rofs, rend, (const int*)scr, dis, h2, b2, out);
}

// Round 13
// 141.061 us; speedup vs baseline: 5.6830x; 1.1020x over previous
//
#include <hip/hip_runtime.h>
#include <hip/hip_fp16.h>

#define NN 100000
#define NE 3200000
#define DF 128
#define HID 32
#define NC 2
#define NBUK 391    // buckets of 256 nodes; bucket = dst >> 8
#define CAP 10240   // scr capacity per bucket (mean 8184, +22 sigma -> no overflow)
#define PEB 8192    // edges per k_part block (391 blocks)

// ws layout (4-byte words):
// [0, NN)              dis (float): rsqrt(deg+1)
// [NN, 2NN)            rofs (int): per-node edge-list start (CAP-strided space)
// [2NN, 3NN)           rend (int): per-node edge-list end
// [3NN, 3NN+400)       cursor (int): bucket cursors; post-part = bucket ends
// [3NN+400, 5NN+400)   h2 (float [NN,2], PRESCALED by dis)
// [5NN+400, 21NN+400)  h1 (fp16 [NN,32], PRESCALED by dis)
// [21NN+400, +NBUK*CAP) scr: packed edges -> (in k_g1, in place) node-sorted csr
// total 21NN + 400 + 391*10240 = 6,104,240 words = 24.4 MB

__global__ void k_zc(int* __restrict__ cursor) {
    int i = threadIdx.x;
    if (i < NBUK) cursor[i] = i * CAP;
}

// partition edges into fixed-capacity bucket regions.
// LDS-sort by bucket, then per-warp COALESCED run emission.
// packed word = src | (dst&255)<<17
__global__ __launch_bounds__(512) void k_part(const int* __restrict__ eidx,
                                              int* __restrict__ cursor,
                                              unsigned* __restrict__ scr) {
    __shared__ unsigned hist[NBUK];
    __shared__ unsigned lofs[NBUK + 1];
    __shared__ unsigned aux[NBUK];
    __shared__ unsigned stage[PEB];      // 32 KB
    __shared__ int sm[512];
    int tid = threadIdx.x;
    int base = blockIdx.x * PEB;

    for (int i = tid; i < NBUK; i += 512) hist[i] = 0u;
    __syncthreads();

    int s[PEB / 512], d[PEB / 512];
#pragma unroll
    for (int i = 0; i < PEB / 512; ++i) {
        int e = base + i * 512 + tid;
        if (e < NE) {
            s[i] = eidx[e];
            d[i] = eidx[NE + e];
            atomicAdd(&hist[d[i] >> 8], 1u);
        } else d[i] = -1;
    }
    __syncthreads();

    int v = (tid < NBUK) ? (int)hist[tid] : 0;
    sm[tid] = v;
    __syncthreads();
    for (int off = 1; off < 512; off <<= 1) {
        int t = (tid >= off) ? sm[tid - off] : 0;
        __syncthreads();
        sm[tid] += t;
        __syncthreads();
    }
    if (tid < NBUK) {
        unsigned excl = (unsigned)(sm[tid] - v);
        lofs[tid] = excl;
        aux[tid] = excl;
    }
    if (tid == 511) lofs[NBUK] = (unsigned)sm[511];
    __syncthreads();

#pragma unroll
    for (int i = 0; i < PEB / 512; ++i) {
        if (d[i] >= 0) {
            unsigned lpos = atomicAdd(&aux[d[i] >> 8], 1u);
            stage[lpos] = (unsigned)s[i] | ((unsigned)(d[i] & 255) << 17);
        }
    }
    __syncthreads();

    for (int i = tid; i < NBUK; i += 512) {
        unsigned c = hist[i];
        hist[i] = c ? (unsigned)atomicAdd(&cursor[i], (int)c) : 0u;
    }
    __syncthreads();

    int warp = tid >> 6, lane = tid & 63;
    for (int i = warp; i < NBUK; i += 8) {
        unsigned lo = lofs[i];
        unsigned n = lofs[i + 1] - lo;
        unsigned gbase = hist[i];
        for (unsigned k = lane; k < n; k += 64)
            scr[gbase + k] = stage[lo + k];
    }
}

// per-bucket degree histogram -> dis (needed before gemm1's prescale)
__global__ __launch_bounds__(256) void k_dis(const unsigned* __restrict__ scr,
                                             const int* __restrict__ cursor,
                                             float* __restrict__ dis) {
    int b = blockIdx.x;
    int cs = b * CAP, ce = cursor[b];
    __shared__ unsigned h[256];
    h[threadIdx.x] = 0u;
    __syncthreads();
    for (int j = cs + threadIdx.x; j < ce; j += 256)
        atomicAdd(&h[(scr[j] >> 17) & 255u], 1u);
    __syncthreads();
    int r = b * 256 + threadIdx.x;
    if (r < NN) dis[r] = rsqrtf((float)(h[threadIdx.x] + 1u));  // +1 = self-loop
}

// h1 = dis[r] * (x @ W1), fp16 [NN,32] (one 64B line per row, prescaled)
__global__ __launch_bounds__(256) void k_gemm1(const float* __restrict__ x,
                                               const float* __restrict__ dis,
                                               const float* __restrict__ W1,
                                               __half* __restrict__ h1) {
    int r = blockIdx.x * blockDim.x + threadIdx.x;
    if (r >= NN) return;
    const float* xr = x + (size_t)r * DF;
    float acc[HID];
#pragma unroll
    for (int c = 0; c < HID; ++c) acc[c] = 0.f;
#pragma unroll
    for (int k = 0; k < DF; k += 4) {
        float4 xv = *reinterpret_cast<const float4*>(xr + k);
#pragma unroll
        for (int c = 0; c < HID; ++c) {
            acc[c] += xv.x * W1[(k + 0) * HID + c];
            acc[c] += xv.y * W1[(k + 1) * HID + c];
            acc[c] += xv.z * W1[(k + 2) * HID + c];
            acc[c] += xv.w * W1[(k + 3) * HID + c];
        }
    }
    float dr = dis[r];
    __half2 pack[HID / 2];
#pragma unroll
    for (int c = 0; c < HID; c += 2)
        pack[c / 2] = __floats2half2_rn(acc[c] * dr, acc[c + 1] * dr);
    float4* dstp = reinterpret_cast<float4*>(h1 + (size_t)r * HID);
    const float4* srcp = reinterpret_cast<const float4*>(pack);
#pragma unroll
    for (int i = 0; i < 4; ++i) dstp[i] = srcp[i];
}

// FUSED build + gather1: one block per bucket.
// pass1: hist; scan -> per-node offsets, dis; pass2: node-sorted LDS scatter;
// writeback node-sorted csr + rofs/rend (for gather2); gather from LDS edge list;
// epilogue +b1/relu/@W2 -> h2 (prescaled).
__global__ __launch_bounds__(512) void k_g1(unsigned* __restrict__ scr,
                                            const int* __restrict__ cursor,
                                            int* __restrict__ rofs, int* __restrict__ rend,
                                            const __half* __restrict__ h1,
                                            const float* __restrict__ b1,
                                            const float* __restrict__ W2,
                                            float* __restrict__ h2) {
    int b = blockIdx.x;
    int cs = b * CAP, ce = cursor[b];
    int n = ce - cs;
    __shared__ unsigned stage[CAP];   // 40 KB, node-sorted src indices
    __shared__ unsigned cnt[256];     // hist -> scatter cursor
    __shared__ int sm[256];
    __shared__ unsigned ofs[257];     // per-node start in stage
    __shared__ float sd[256];         // per-node dis
    int tid = threadIdx.x;

    if (tid < 256) cnt[tid] = 0u;
    __syncthreads();
    // pass 1: histogram
    for (int j = tid; j < n; j += 512)
        atomicAdd(&cnt[(scr[cs + j] >> 17) & 255u], 1u);
    __syncthreads();
    // scan (first 256 threads)
    int v = 0;
    if (tid < 256) { v = (int)cnt[tid]; sm[tid] = v; }
    __syncthreads();
    for (int off = 1; off < 256; off <<= 1) {
        int t = 0;
        if (tid < 256 && tid >= off) t = sm[tid - off];
        __syncthreads();
        if (tid < 256) sm[tid] += t;
        __syncthreads();
    }
    if (tid < 256) {
        int excl = sm[tid] - v;
        ofs[tid] = (unsigned)excl;
        cnt[tid] = (unsigned)excl;            // scatter cursor
        sd[tid] = rsqrtf((float)(v + 1));     // +1 = self-loop
        if (tid == 255) ofs[256] = (unsigned)(excl + v);
        int node = b * 256 + tid;
        if (node < NN) {                      // for gather2
            rofs[node] = cs + excl;
            rend[node] = cs + excl + v;
        }
    }
    __syncthreads();
    // pass 2: node-sorted scatter into LDS
    for (int j = tid; j < n; j += 512) {
        unsigned w = scr[cs + j];
        unsigned pos = atomicAdd(&cnt[(w >> 17) & 255u], 1u);
        stage[pos] = w & 0x1FFFFu;
    }
    __syncthreads();
    // writeback node-sorted csr (coalesced) for gather2
    for (int j = tid; j < n; j += 512) scr[cs + j] = stage[j];

    // gather: 4 lanes/node, 128 groups x 2 node-iterations
    const float4* hv = reinterpret_cast<const float4*>(h1);
    int p = tid & 3;
#pragma unroll
    for (int it = 0; it < 2; ++it) {
        int rl = (tid >> 2) + it * 128;
        int st = (int)ofs[rl], en = (int)ofs[rl + 1];
        float a[8];
#pragma unroll
        for (int k = 0; k < 8; ++k) a[k] = 0.f;

#define ACC4(q)                                                           \
    {                                                                     \
        const __half2* hp = reinterpret_cast<const __half2*>(&(q));       \
        _Pragma("unroll") for (int k = 0; k < 4; ++k) {                   \
            float2 f = __half22float2(hp[k]);                             \
            a[2 * k] += f.x;                                              \
            a[2 * k + 1] += f.y;                                          \
        }                                                                 \
    }
        int j = st;
        for (; j + 7 < en; j += 8) {
            unsigned s0 = stage[j], s1 = stage[j + 1], s2 = stage[j + 2], s3 = stage[j + 3];
            unsigned s4 = stage[j + 4], s5 = stage[j + 5], s6 = stage[j + 6], s7 = stage[j + 7];
            float4 q0 = hv[(size_t)s0 * 4 + p];
            float4 q1 = hv[(size_t)s1 * 4 + p];
            float4 q2 = hv[(size_t)s2 * 4 + p];
            float4 q3 = hv[(size_t)s3 * 4 + p];
            float4 q4 = hv[(size_t)s4 * 4 + p];
            float4 q5 = hv[(size_t)s5 * 4 + p];
            float4 q6 = hv[(size_t)s6 * 4 + p];
            float4 q7 = hv[(size_t)s7 * 4 + p];
            ACC4(q0) ACC4(q1) ACC4(q2) ACC4(q3)
            ACC4(q4) ACC4(q5) ACC4(q6) ACC4(q7)
        }
        for (; j < en; ++j) {
            unsigned s0 = stage[j];
            float4 q0 = hv[(size_t)s0 * 4 + p];
            ACC4(q0)
        }
        int rg = b * 256 + rl;
        if (rg < NN) {
            float4 qs = hv[(size_t)rg * 4 + p];   // self term (prescaled)
            ACC4(qs)
            float dr = sd[rl];
            int c = p * 8;
            float4 bl = *reinterpret_cast<const float4*>(b1 + c);
            float4 bh = *reinterpret_cast<const float4*>(b1 + c + 4);
            float vv[8];
            vv[0] = fmaxf(dr * a[0] + bl.x, 0.f); vv[1] = fmaxf(dr * a[1] + bl.y, 0.f);
            vv[2] = fmaxf(dr * a[2] + bl.z, 0.f); vv[3] = fmaxf(dr * a[3] + bl.w, 0.f);
            vv[4] = fmaxf(dr * a[4] + bh.x, 0.f); vv[5] = fmaxf(dr * a[5] + bh.y, 0.f);
            vv[6] = fmaxf(dr * a[6] + bh.z, 0.f); vv[7] = fmaxf(dr * a[7] + bh.w, 0.f);
            float o0 = 0.f, o1 = 0.f;
#pragma unroll
            for (int k = 0; k < 8; ++k) {
                o0 += vv[k] * W2[(c + k) * NC + 0];
                o1 += vv[k] * W2[(c + k) * NC + 1];
            }
            o0 += __shfl_xor(o0, 1); o1 += __shfl_xor(o1, 1);
            o0 += __shfl_xor(o0, 2); o1 += __shfl_xor(o1, 2);
            if (p == 0) {
                h2[2 * (size_t)rg + 0] = dr * o0;   // prescale for layer 2
                h2[2 * (size_t)rg + 1] = dr * o1;
            }
        }
#undef ACC4
    }
}

// gather-aggregate layer 2 (h2 prescaled) + log_softmax -> out
__global__ void k_gather2(const int* __restrict__ rofs, const int* __restrict__ rend,
                          const int* __restrict__ csr, const float* __restrict__ dis,
                          const float* __restrict__ h2, const float* __restrict__ b2,
                          float* __restrict__ out) {
    int r = blockIdx.x * blockDim.x + threadIdx.x;
    if (r >= NN) return;
    int start = rofs[r], end = rend[r];
    float a0 = 0.f, a1 = 0.f;
    int j = start;
    for (; j + 3 < end; j += 4) {
        int s0 = csr[j], s1 = csr[j + 1], s2 = csr[j + 2], s3 = csr[j + 3];
        float2 v0 = *(const float2*)(h2 + 2 * (size_t)s0);
        float2 v1 = *(const float2*)(h2 + 2 * (size_t)s1);
        float2 v2 = *(const float2*)(h2 + 2 * (size_t)s2);
        float2 v3 = *(const float2*)(h2 + 2 * (size_t)s3);
        a0 += v0.x + v1.x + v2.x + v3.x;
        a1 += v0.y + v1.y + v2.y + v3.y;
    }
    for (; j < end; ++j) {
        float2 v = *(const float2*)(h2 + 2 * (size_t)csr[j]);
        a0 += v.x;
        a1 += v.y;
    }
    float dr = dis[r];
    float2 own = *(const float2*)(h2 + 2 * (size_t)r);
    float l0 = dr * (a0 + own.x) + b2[0];
    float l1 = dr * (a1 + own.y) + b2[1];
    float m = fmaxf(l0, l1);
    float lse = m + logf(expf(l0 - m) + expf(l1 - m));
    out[2 * (size_t)r + 0] = l0 - lse;
    out[2 * (size_t)r + 1] = l1 - lse;
}

extern "C" void kernel_launch(void* const* d_in, const int* in_sizes, int n_in,
                              void* d_out, int out_size, void* d_ws, size_t ws_size,
                              hipStream_t stream) {
    const float* x  = (const float*)d_in[0];
    const int* ei   = (const int*)d_in[1];   // [2, NE] int32
    const float* W1 = (const float*)d_in[2];
    const float* b1 = (const float*)d_in[3];
    const float* W2 = (const float*)d_in[4];
    const float* b2 = (const float*)d_in[5];
    float* out      = (float*)d_out;

    float* ws     = (float*)d_ws;
    float* dis    = ws;
    int* rofs     = (int*)(ws + (size_t)NN);
    int* rend     = (int*)(ws + (size_t)2 * NN);
    int* cursor   = (int*)(ws + (size_t)3 * NN);
    float* h2     = ws + (size_t)3 * NN + 400;
    __half* h1    = (__half*)(ws + (size_t)5 * NN + 400);
    unsigned* scr = (unsigned*)(ws + (size_t)21 * NN + 400);  // -> csr in place

    k_zc<<<1, 512, 0, stream>>>(cursor);
    k_part<<<(NE + PEB - 1) / PEB, 512, 0, stream>>>(ei, cursor, scr);
    k_dis<<<NBUK, 256, 0, stream>>>(scr, cursor, dis);
    k_gemm1<<<(NN + 255) / 256, 256, 0, stream>>>(x, dis, W1, h1);
    k_g1<<<NBUK, 512, 0, stream>>>(scr, cursor, rofs, rend, h1, b1, W2, h2);
    k_gather2<<<(NN + 255) / 256, 256, 0, stream>>>(rofs, rend, (const int*)scr, dis, h2, b2, out);
}

// Round 14
// 133.318 us; speedup vs baseline: 6.0131x; 1.0581x over previous
//
#include <hip/hip_runtime.h>
#include <hip/hip_fp16.h>

#define NN 100000
#define NE 3200000
#define DF 128
#define HID 32
#define NC 2
#define NBUK 782    // buckets of 128 nodes; bucket = dst >> 7 (782*128 = 100096)
#define CAP 5376    // per-bucket capacity (mean 4092, sigma 64 -> +20 sigma)
#define PEB 8192    // edges per k_part block (391 blocks)

// ws layout (4-byte words):
// [0, NN)              dis (float): rsqrt(deg+1)
// [NN, 2NN)            rofs (int): per-node edge-list start (CAP-strided space)
// [2NN, 3NN)           rend (int): per-node edge-list end
// [3NN, 3NN+800)       cursor (int): bucket cursors; post-part = bucket ends
// [3NN+800, 5NN+800)   h2 (float [NN,2], PRESCALED by dis)
// [5NN+800, 21NN+800)  h1 (fp16 [NN,32], PRESCALED by dis)
// [21NN+800, +NBUK*CAP) scr: packed edges -> (in k_g1, in place) node-sorted csr
// total 21NN + 800 + 782*5376 = 6,304,832 words = 25.2 MB

__global__ void k_zc(int* __restrict__ cursor) {
    int i = threadIdx.x;
    if (i < NBUK) cursor[i] = i * CAP;
}

// partition edges into fixed-capacity bucket regions.
// LDS-sort by bucket, then 16-lane-group coalesced run emission.
// packed word = src | (dst&127)<<17
__global__ __launch_bounds__(512) void k_part(const int* __restrict__ eidx,
                                              int* __restrict__ cursor,
                                              unsigned* __restrict__ scr) {
    __shared__ unsigned hist[NBUK];      // counts -> global bases
    __shared__ unsigned lofs[NBUK + 1];  // local exclusive offsets (+ total)
    __shared__ unsigned aux[NBUK];       // local scatter cursor
    __shared__ unsigned stage[PEB];      // 32 KB bucket-sorted stage
    __shared__ int sm[512];
    int tid = threadIdx.x;
    int base = blockIdx.x * PEB;

    for (int i = tid; i < NBUK; i += 512) hist[i] = 0u;
    __syncthreads();

    int s[PEB / 512], d[PEB / 512];
#pragma unroll
    for (int i = 0; i < PEB / 512; ++i) {
        int e = base + i * 512 + tid;
        if (e < NE) {
            s[i] = eidx[e];
            d[i] = eidx[NE + e];
            atomicAdd(&hist[d[i] >> 7], 1u);
        } else d[i] = -1;
    }
    __syncthreads();

    // pair-per-thread exclusive scan over 782 = 2*391 bins
    int a = 0, b2 = 0;
    if (tid < NBUK / 2) { a = (int)hist[2 * tid]; b2 = (int)hist[2 * tid + 1]; }
    sm[tid] = a + b2;
    __syncthreads();
    for (int off = 1; off < 512; off <<= 1) {
        int t = (tid >= off) ? sm[tid - off] : 0;
        __syncthreads();
        sm[tid] += t;
        __syncthreads();
    }
    if (tid < NBUK / 2) {
        unsigned excl = (unsigned)(sm[tid] - (a + b2));
        lofs[2 * tid] = excl;         aux[2 * tid] = excl;
        lofs[2 * tid + 1] = excl + a; aux[2 * tid + 1] = excl + (unsigned)a;
    }
    if (tid == 511) lofs[NBUK] = (unsigned)sm[511];  // total valid edges
    __syncthreads();

    // LDS scatter -> bucket-sorted stage
#pragma unroll
    for (int i = 0; i < PEB / 512; ++i) {
        if (d[i] >= 0) {
            unsigned lpos = atomicAdd(&aux[d[i] >> 7], 1u);
            stage[lpos] = (unsigned)s[i] | ((unsigned)(d[i] & 127) << 17);
        }
    }
    __syncthreads();

    // reserve global space: one returning atomic per nonzero bucket
    for (int i = tid; i < NBUK; i += 512) {
        unsigned c = hist[i];
        hist[i] = c ? (unsigned)atomicAdd(&cursor[i], (int)c) : 0u;
    }
    __syncthreads();

    // 16-lane-group run emission: consecutive lanes -> consecutive addresses
    int grp = tid >> 4, lane = tid & 15;
    for (int i = grp; i < NBUK; i += 32) {
        unsigned lo = lofs[i];
        unsigned n = lofs[i + 1] - lo;
        unsigned gbase = hist[i];
        for (unsigned k = lane; k < n; k += 16)
            scr[gbase + k] = stage[lo + k];
    }
}

// per-bucket degree histogram -> dis (needed before gemm1's prescale)
__global__ __launch_bounds__(256) void k_dis(const unsigned* __restrict__ scr,
                                             const int* __restrict__ cursor,
                                             float* __restrict__ dis) {
    int b = blockIdx.x;
    int cs = b * CAP, ce = cursor[b];
    __shared__ unsigned h[128];
    if (threadIdx.x < 128) h[threadIdx.x] = 0u;
    __syncthreads();
    for (int j = cs + threadIdx.x; j < ce; j += 256)
        atomicAdd(&h[(scr[j] >> 17) & 127u], 1u);
    __syncthreads();
    int r = b * 128 + threadIdx.x;
    if (threadIdx.x < 128 && r < NN)
        dis[r] = rsqrtf((float)(h[threadIdx.x] + 1u));  // +1 = self-loop
}

// h1 = dis[r] * (x @ W1), fp16 [NN,32] (one 64B line per row, prescaled)
__global__ __launch_bounds__(256) void k_gemm1(const float* __restrict__ x,
                                               const float* __restrict__ dis,
                                               const float* __restrict__ W1,
                                               __half* __restrict__ h1) {
    int r = blockIdx.x * blockDim.x + threadIdx.x;
    if (r >= NN) return;
    const float* xr = x + (size_t)r * DF;
    float acc[HID];
#pragma unroll
    for (int c = 0; c < HID; ++c) acc[c] = 0.f;
#pragma unroll
    for (int k = 0; k < DF; k += 4) {
        float4 xv = *reinterpret_cast<const float4*>(xr + k);
#pragma unroll
        for (int c = 0; c < HID; ++c) {
            acc[c] += xv.x * W1[(k + 0) * HID + c];
            acc[c] += xv.y * W1[(k + 1) * HID + c];
            acc[c] += xv.z * W1[(k + 2) * HID + c];
            acc[c] += xv.w * W1[(k + 3) * HID + c];
        }
    }
    float dr = dis[r];
    __half2 pack[HID / 2];
#pragma unroll
    for (int c = 0; c < HID; c += 2)
        pack[c / 2] = __floats2half2_rn(acc[c] * dr, acc[c + 1] * dr);
    float4* dstp = reinterpret_cast<float4*>(h1 + (size_t)r * HID);
    const float4* srcp = reinterpret_cast<const float4*>(pack);
#pragma unroll
    for (int i = 0; i < 4; ++i) dstp[i] = srcp[i];
}

// FUSED build + gather1: one block per 128-node bucket (LDS ~23.6 KB -> high occupancy).
// pass1: hist; scan -> per-node offsets, dis; pass2: node-sorted LDS scatter;
// writeback node-sorted csr + rofs/rend (for gather2); gather from LDS edge list;
// epilogue +b1/relu/@W2 -> h2 (prescaled).
__global__ __launch_bounds__(512) void k_g1(unsigned* __restrict__ scr,
                                            const int* __restrict__ cursor,
                                            int* __restrict__ rofs, int* __restrict__ rend,
                                            const __half* __restrict__ h1,
                                            const float* __restrict__ b1,
                                            const float* __restrict__ W2,
                                            float* __restrict__ h2) {
    int b = blockIdx.x;
    int cs = b * CAP, ce = cursor[b];
    int n = ce - cs;
    __shared__ unsigned stage[CAP];   // 21.5 KB, node-sorted src indices
    __shared__ unsigned cnt[128];     // hist -> scatter cursor
    __shared__ int sm[128];
    __shared__ unsigned ofs[129];     // per-node start in stage
    __shared__ float sd[128];         // per-node dis
    int tid = threadIdx.x;

    if (tid < 128) cnt[tid] = 0u;
    __syncthreads();
    // pass 1: histogram
    for (int j = tid; j < n; j += 512)
        atomicAdd(&cnt[(scr[cs + j] >> 17) & 127u], 1u);
    __syncthreads();
    // scan (first 128 threads)
    int v = 0;
    if (tid < 128) { v = (int)cnt[tid]; sm[tid] = v; }
    __syncthreads();
    for (int off = 1; off < 128; off <<= 1) {
        int t = 0;
        if (tid < 128 && tid >= off) t = sm[tid - off];
        __syncthreads();
        if (tid < 128) sm[tid] += t;
        __syncthreads();
    }
    if (tid < 128) {
        int excl = sm[tid] - v;
        ofs[tid] = (unsigned)excl;
        cnt[tid] = (unsigned)excl;            // scatter cursor
        sd[tid] = rsqrtf((float)(v + 1));     // +1 = self-loop
        if (tid == 127) ofs[128] = (unsigned)(excl + v);
        int node = b * 128 + tid;
        if (node < NN) {                      // for gather2
            rofs[node] = cs + excl;
            rend[node] = cs + excl + v;
        }
    }
    __syncthreads();
    // pass 2: node-sorted scatter into LDS
    for (int j = tid; j < n; j += 512) {
        unsigned w = scr[cs + j];
        unsigned pos = atomicAdd(&cnt[(w >> 17) & 127u], 1u);
        stage[pos] = w & 0x1FFFFu;
    }
    __syncthreads();
    // writeback node-sorted csr (coalesced) for gather2
    for (int j = tid; j < n; j += 512) scr[cs + j] = stage[j];

    // gather: 4 lanes/node x 128 nodes = 512 threads
    const float4* hv = reinterpret_cast<const float4*>(h1);
    int p = tid & 3;
    int rl = tid >> 2;
    int st = (int)ofs[rl], en = (int)ofs[rl + 1];
    float a[8];
#pragma unroll
    for (int k = 0; k < 8; ++k) a[k] = 0.f;

#define ACC4(q)                                                           \
    {                                                                     \
        const __half2* hp = reinterpret_cast<const __half2*>(&(q));       \
        _Pragma("unroll") for (int k = 0; k < 4; ++k) {                   \
            float2 f = __half22float2(hp[k]);                             \
            a[2 * k] += f.x;                                              \
            a[2 * k + 1] += f.y;                                          \
        }                                                                 \
    }
    int j = st;
    for (; j + 7 < en; j += 8) {
        unsigned s0 = stage[j], s1 = stage[j + 1], s2 = stage[j + 2], s3 = stage[j + 3];
        unsigned s4 = stage[j + 4], s5 = stage[j + 5], s6 = stage[j + 6], s7 = stage[j + 7];
        float4 q0 = hv[(size_t)s0 * 4 + p];
        float4 q1 = hv[(size_t)s1 * 4 + p];
        float4 q2 = hv[(size_t)s2 * 4 + p];
        float4 q3 = hv[(size_t)s3 * 4 + p];
        float4 q4 = hv[(size_t)s4 * 4 + p];
        float4 q5 = hv[(size_t)s5 * 4 + p];
        float4 q6 = hv[(size_t)s6 * 4 + p];
        float4 q7 = hv[(size_t)s7 * 4 + p];
        ACC4(q0) ACC4(q1) ACC4(q2) ACC4(q3)
        ACC4(q4) ACC4(q5) ACC4(q6) ACC4(q7)
    }
    for (; j < en; ++j) {
        unsigned s0 = stage[j];
        float4 q0 = hv[(size_t)s0 * 4 + p];
        ACC4(q0)
    }
    int rg = b * 128 + rl;
    if (rg < NN) {
        float4 qs = hv[(size_t)rg * 4 + p];   // self term (prescaled)
        ACC4(qs)
        float dr = sd[rl];
        int c = p * 8;
        float4 bl = *reinterpret_cast<const float4*>(b1 + c);
        float4 bh = *reinterpret_cast<const float4*>(b1 + c + 4);
        float vv[8];
        vv[0] = fmaxf(dr * a[0] + bl.x, 0.f); vv[1] = fmaxf(dr * a[1] + bl.y, 0.f);
        vv[2] = fmaxf(dr * a[2] + bl.z, 0.f); vv[3] = fmaxf(dr * a[3] + bl.w, 0.f);
        vv[4] = fmaxf(dr * a[4] + bh.x, 0.f); vv[5] = fmaxf(dr * a[5] + bh.y, 0.f);
        vv[6] = fmaxf(dr * a[6] + bh.z, 0.f); vv[7] = fmaxf(dr * a[7] + bh.w, 0.f);
        float o0 = 0.f, o1 = 0.f;
#pragma unroll
        for (int k = 0; k < 8; ++k) {
            o0 += vv[k] * W2[(c + k) * NC + 0];
            o1 += vv[k] * W2[(c + k) * NC + 1];
        }
        o0 += __shfl_xor(o0, 1); o1 += __shfl_xor(o1, 1);
        o0 += __shfl_xor(o0, 2); o1 += __shfl_xor(o1, 2);
        if (p == 0) {
            h2[2 * (size_t)rg + 0] = dr * o0;   // prescale for layer 2
            h2[2 * (size_t)rg + 1] = dr * o1;
        }
    }
#undef ACC4
}

// gather-aggregate layer 2 (h2 prescaled) + log_softmax -> out
__global__ void k_gather2(const int* __restrict__ rofs, const int* __restrict__ rend,
                          const int* __restrict__ csr, const float* __restrict__ dis,
                          const float* __restrict__ h2, const float* __restrict__ b2,
                          float* __restrict__ out) {
    int r = blockIdx.x * blockDim.x + threadIdx.x;
    if (r >= NN) return;
    int start = rofs[r], end = rend[r];
    float a0 = 0.f, a1 = 0.f;
    int j = start;
    for (; j + 3 < end; j += 4) {
        int s0 = csr[j], s1 = csr[j + 1], s2 = csr[j + 2], s3 = csr[j + 3];
        float2 v0 = *(const float2*)(h2 + 2 * (size_t)s0);
        float2 v1 = *(const float2*)(h2 + 2 * (size_t)s1);
        float2 v2 = *(const float2*)(h2 + 2 * (size_t)s2);
        float2 v3 = *(const float2*)(h2 + 2 * (size_t)s3);
        a0 += v0.x + v1.x + v2.x + v3.x;
        a1 += v0.y + v1.y + v2.y + v3.y;
    }
    for (; j < end; ++j) {
        float2 v = *(const float2*)(h2 + 2 * (size_t)csr[j]);
        a0 += v.x;
        a1 += v.y;
    }
    float dr = dis[r];
    float2 own = *(const float2*)(h2 + 2 * (size_t)r);
    float l0 = dr * (a0 + own.x) + b2[0];
    float l1 = dr * (a1 + own.y) + b2[1];
    float m = fmaxf(l0, l1);
    float lse = m + logf(expf(l0 - m) + expf(l1 - m));
    out[2 * (size_t)r + 0] = l0 - lse;
    out[2 * (size_t)r + 1] = l1 - lse;
}

extern "C" void kernel_launch(void* const* d_in, const int* in_sizes, int n_in,
                              void* d_out, int out_size, void* d_ws, size_t ws_size,
                              hipStream_t stream) {
    const float* x  = (const float*)d_in[0];
    const int* ei   = (const int*)d_in[1];   // [2, NE] int32
    const float* W1 = (const float*)d_in[2];
    const float* b1 = (const float*)d_in[3];
    const float* W2 = (const float*)d_in[4];
    const float* b2 = (const float*)d_in[5];
    float* out      = (float*)d_out;

    float* ws     = (float*)d_ws;
    float* dis    = ws;
    int* rofs     = (int*)(ws + (size_t)NN);
    int* rend     = (int*)(ws + (size_t)2 * NN);
    int* cursor   = (int*)(ws + (size_t)3 * NN);
    float* h2     = ws + (size_t)3 * NN + 800;
    __half* h1    = (__half*)(ws + (size_t)5 * NN + 800);
    unsigned* scr = (unsigned*)(ws + (size_t)21 * NN + 800);  // -> csr in place

    k_zc<<<1, 1024, 0, stream>>>(cursor);
    k_part<<<(NE + PEB - 1) / PEB, 512, 0, stream>>>(ei, cursor, scr);
    k_dis<<<NBUK, 256, 0, stream>>>(scr, cursor, dis);
    k_gemm1<<<(NN + 255) / 256, 256, 0, stream>>>(x, dis, W1, h1);
    k_g1<<<NBUK, 512, 0, stream>>>(scr, cursor, rofs, rend, h1, b1, W2, h2);
    k_gather2<<<(NN + 255) / 256, 256, 0, stream>>>(rofs, rend, (const int*)scr, dis, h2, b2, out);
}